// Round 5
// baseline (200.635 us; speedup 1.0000x reference)
//
#include <hip/hip_runtime.h>
#include <stddef.h>

#define IMG_N 4096

typedef float vf4 __attribute__((ext_vector_type(4)));

// LDS layout (float offsets), total 10,192 floats = 40,768 B -> 4 blocks/CU
// (4 x 40,960B rounded = 160 KiB exactly).
// Level-1 subbands 40x40 @ stride 40 (16B-aligned rows). Level-2 @ 20.
// Level-3 @ 10. HH1C/LL1P 32x32 @ 36. HH2C/LL2P 16x16 @ 20.
// NOTE: level-2/3 subbands and HH2C/LL2P have REAL slots (not aliased onto
// HH1) because the serial wave writes them concurrently with conv7's HH1
// reads in phase P2. Only alias: LL1P -> LL1 slot (LL1 dead after the serial
// wave's DWT2, which completes before barrier B2; LL1P written after B2).
#define S_LH1   0        // 1600
#define S_HL1   1600     // 1600
#define S_HH1   3200     // 1600
#define S_LL1   4800     // 1600  (aliased by LL1P after B2)
#define S_HH1C  6400     // 1152
#define S_LL2   7552     // 400
#define S_LH2   7952     // 400
#define S_HL2   8352     // 400
#define S_HH2   8752     // 400
#define S_HH2C  9152     // 320
#define S_LL3   9472     // 100
#define S_LH3   9572     // 100
#define S_HL3   9672     // 100
#define S_HH3   9772     // 100
#define S_LL2P  9872     // 320
#define S_TOTAL 10192

#define S_LL1P  (S_LL1)

static __device__ __forceinline__ void wave_fence() {
    __builtin_amdgcn_wave_barrier();
    __builtin_amdgcn_s_waitcnt(0);
    __builtin_amdgcn_wave_barrier();
}

__global__ __launch_bounds__(512, 8) void haar_fused(
    const float* __restrict__ x,
    const float* __restrict__ w3, const float* __restrict__ b3,
    const float* __restrict__ w5, const float* __restrict__ b5,
    const float* __restrict__ w7, const float* __restrict__ b7,
    float* __restrict__ out)
{
    __shared__ __align__(16) float sm[S_TOTAL];
    const int tid = threadIdx.x;
    const int bx = blockIdx.x, by = blockIdx.y;
    const int R0 = by * 64, C0 = bx * 64;

    float* LH1 = sm + S_LH1;   float* HL1 = sm + S_HL1;
    float* HH1 = sm + S_HH1;   float* LL1 = sm + S_LL1;
    float* HH1C = sm + S_HH1C;
    float* LL2 = sm + S_LL2;   float* LH2 = sm + S_LH2;
    float* HL2 = sm + S_HL2;   float* HH2 = sm + S_HH2;
    float* HH2C = sm + S_HH2C;
    float* LL3 = sm + S_LL3;   float* LH3 = sm + S_LH3;
    float* HL3 = sm + S_HL3;   float* HH3 = sm + S_HH3;
    float* LL1P = sm + S_LL1P; float* LL2P = sm + S_LL2P;

    // ==== P1: global load + level-1 DWT. 400 items = 40 rows x 10 groups. ====
    const bool interior = (by >= 1) && (by <= 62) && (bx >= 1) && (bx <= 62);
    if (tid < 400) {
        const int u = tid / 10, g = tid % 10;
        float4 t0, t1, bb0, bb1;
        if (interior) {
            const float* p = x + (size_t)(R0 - 8 + 2 * u) * IMG_N + (C0 - 8 + 8 * g);
            t0  = *(const float4*)(p);
            t1  = *(const float4*)(p + 4);
            bb0 = *(const float4*)(p + IMG_N);
            bb1 = *(const float4*)(p + IMG_N + 4);
        } else {
            const int gr0 = R0 - 8 + 2 * u, gr1 = gr0 + 1;
            const int gc = C0 - 8 + 8 * g;
            const bool r0v = (gr0 >= 0 && gr0 < IMG_N), r1v = (gr1 >= 0 && gr1 < IMG_N);
            float tv[8], bv[8];
            #pragma unroll
            for (int k = 0; k < 8; ++k) {
                int gck = gc + k;
                bool cv = (gck >= 0 && gck < IMG_N);
                tv[k] = (r0v && cv) ? x[(size_t)gr0 * IMG_N + gck] : 0.0f;
                bv[k] = (r1v && cv) ? x[(size_t)gr1 * IMG_N + gck] : 0.0f;
            }
            t0  = make_float4(tv[0], tv[1], tv[2], tv[3]);
            t1  = make_float4(tv[4], tv[5], tv[6], tv[7]);
            bb0 = make_float4(bv[0], bv[1], bv[2], bv[3]);
            bb1 = make_float4(bv[4], bv[5], bv[6], bv[7]);
        }
        float4 llv, lhv, hlv, hhv;
        {
            float a = t0.x, b = t0.y, c = bb0.x, d = bb0.y;
            llv.x = (a + b + c + d) * 0.5f; lhv.x = (a + b - c - d) * 0.5f;
            hlv.x = (a - b + c - d) * 0.5f; hhv.x = (a - b - c + d) * 0.5f;
            a = t0.z; b = t0.w; c = bb0.z; d = bb0.w;
            llv.y = (a + b + c + d) * 0.5f; lhv.y = (a + b - c - d) * 0.5f;
            hlv.y = (a - b + c - d) * 0.5f; hhv.y = (a - b - c + d) * 0.5f;
            a = t1.x; b = t1.y; c = bb1.x; d = bb1.y;
            llv.z = (a + b + c + d) * 0.5f; lhv.z = (a + b - c - d) * 0.5f;
            hlv.z = (a - b + c - d) * 0.5f; hhv.z = (a - b - c + d) * 0.5f;
            a = t1.z; b = t1.w; c = bb1.z; d = bb1.w;
            llv.w = (a + b + c + d) * 0.5f; lhv.w = (a + b - c - d) * 0.5f;
            hlv.w = (a - b + c - d) * 0.5f; hhv.w = (a - b - c + d) * 0.5f;
        }
        const int o = u * 40 + 4 * g;
        *(float4*)(LL1 + o) = llv;  *(float4*)(LH1 + o) = lhv;
        *(float4*)(HL1 + o) = hlv;  *(float4*)(HH1 + o) = hhv;
    }
    __syncthreads();   // B1

    // ==== P2: conv7 on waves 0-1 || serial mid-level chain on wave 4 ====
    if (tid < 128) {
        // conv7 on HH1: 2x4-output strip per thread. Out rows 2*i2, 2*i2+1.
        // Out row rr taps HH1 local rows rr+1..rr+7, cols j+1..j+7.
        const int i2 = tid >> 3;            // 0..15
        const int j0 = (tid & 7) << 2;      // 0,4,...,28
        const float bias = b7[0];
        float a0 = bias, a1 = bias, a2 = bias, a3 = bias;   // row 2*i2
        float c0 = bias, c1 = bias, c2 = bias, c3 = bias;   // row 2*i2+1
        #pragma unroll
        for (int k = 0; k < 8; ++k) {       // HH1 local rows 2*i2+1+k
            const float* rp = HH1 + (2 * i2 + 1 + k) * 40 + j0;
            float4 A = *(const float4*)(rp);
            float4 B = *(const float4*)(rp + 4);
            float4 C = *(const float4*)(rp + 8);
            if (k <= 6) {                   // dy = k for out row 2*i2
                const float* wr = w7 + k * 7;
                float q0 = wr[0], q1 = wr[1], q2 = wr[2], q3 = wr[3],
                      q4 = wr[4], q5 = wr[5], q6 = wr[6];
                a0 += q0*A.y + q1*A.z + q2*A.w + q3*B.x + q4*B.y + q5*B.z + q6*B.w;
                a1 += q0*A.z + q1*A.w + q2*B.x + q3*B.y + q4*B.z + q5*B.w + q6*C.x;
                a2 += q0*A.w + q1*B.x + q2*B.y + q3*B.z + q4*B.w + q5*C.x + q6*C.y;
                a3 += q0*B.x + q1*B.y + q2*B.z + q3*B.w + q4*C.x + q5*C.y + q6*C.z;
            }
            if (k >= 1) {                   // dy = k-1 for out row 2*i2+1
                const float* wr = w7 + (k - 1) * 7;
                float q0 = wr[0], q1 = wr[1], q2 = wr[2], q3 = wr[3],
                      q4 = wr[4], q5 = wr[5], q6 = wr[6];
                c0 += q0*A.y + q1*A.z + q2*A.w + q3*B.x + q4*B.y + q5*B.z + q6*B.w;
                c1 += q0*A.z + q1*A.w + q2*B.x + q3*B.y + q4*B.z + q5*B.w + q6*C.x;
                c2 += q0*A.w + q1*B.x + q2*B.y + q3*B.z + q4*B.w + q5*C.x + q6*C.y;
                c3 += q0*B.x + q1*B.y + q2*B.z + q3*B.w + q4*C.x + q5*C.y + q6*C.z;
            }
        }
        *(float4*)(HH1C + (2 * i2) * 36 + j0)     = make_float4(a0, a1, a2, a3);
        *(float4*)(HH1C + (2 * i2 + 1) * 36 + j0) = make_float4(c0, c1, c2, c3);
    } else if (tid >= 256 && tid < 320) {
        const int lane = tid - 256;
        // --- DWT2: LL1 (40x40 @40) -> 20x20 @20. 100 items, 2/lane. ---
        #pragma unroll
        for (int k = 0; k < 2; ++k) {
            const int t = lane + 64 * k;
            if (t < 100) {
                const int u = t / 5, g = t % 5;
                const float* rp = LL1 + (2 * u) * 40 + 8 * g;
                float4 t0 = *(const float4*)(rp),      t1 = *(const float4*)(rp + 4);
                float4 c0 = *(const float4*)(rp + 40), c1 = *(const float4*)(rp + 44);
                float4 llv, lhv, hlv, hhv;
                llv.x = (t0.x + t0.y + c0.x + c0.y) * 0.5f; lhv.x = (t0.x + t0.y - c0.x - c0.y) * 0.5f;
                hlv.x = (t0.x - t0.y + c0.x - c0.y) * 0.5f; hhv.x = (t0.x - t0.y - c0.x + c0.y) * 0.5f;
                llv.y = (t0.z + t0.w + c0.z + c0.w) * 0.5f; lhv.y = (t0.z + t0.w - c0.z - c0.w) * 0.5f;
                hlv.y = (t0.z - t0.w + c0.z - c0.w) * 0.5f; hhv.y = (t0.z - t0.w - c0.z + c0.w) * 0.5f;
                llv.z = (t1.x + t1.y + c1.x + c1.y) * 0.5f; lhv.z = (t1.x + t1.y - c1.x - c1.y) * 0.5f;
                hlv.z = (t1.x - t1.y + c1.x - c1.y) * 0.5f; hhv.z = (t1.x - t1.y - c1.x + c1.y) * 0.5f;
                llv.w = (t1.z + t1.w + c1.z + c1.w) * 0.5f; lhv.w = (t1.z + t1.w - c1.z - c1.w) * 0.5f;
                hlv.w = (t1.z - t1.w + c1.z - c1.w) * 0.5f; hhv.w = (t1.z - t1.w - c1.z + c1.w) * 0.5f;
                const int o = u * 20 + 4 * g;
                *(float4*)(LL2 + o) = llv;  *(float4*)(LH2 + o) = lhv;
                *(float4*)(HL2 + o) = hlv;  *(float4*)(HH2 + o) = hhv;
            }
        }
        wave_fence();
        // --- DWT3: LL2 -> level-3 10x10 @10 (lanes 0-49) ---
        if (lane < 50) {
            const int u = lane / 5, v2 = (lane % 5) * 2;
            const float* rp = LL2 + (2 * u) * 20 + 2 * v2;
            float4 t0 = *(const float4*)(rp);
            float4 c0 = *(const float4*)(rp + 20);
            const int o = u * 10 + v2;
            *(float2*)(LL3 + o) = make_float2((t0.x + t0.y + c0.x + c0.y) * 0.5f,
                                              (t0.z + t0.w + c0.z + c0.w) * 0.5f);
            *(float2*)(LH3 + o) = make_float2((t0.x + t0.y - c0.x - c0.y) * 0.5f,
                                              (t0.z + t0.w - c0.z - c0.w) * 0.5f);
            *(float2*)(HL3 + o) = make_float2((t0.x - t0.y + c0.x - c0.y) * 0.5f,
                                              (t0.z - t0.w + c0.z - c0.w) * 0.5f);
            *(float2*)(HH3 + o) = make_float2((t0.x - t0.y - c0.x + c0.y) * 0.5f,
                                              (t0.z - t0.w - c0.z + c0.w) * 0.5f);
        }
        // --- conv5 on HH2: 16x16 outputs, 1x4 strip per lane (64 strips) ---
        {
            const int i = lane >> 2;
            const int j0 = (lane & 3) << 2;
            const float bias = b5[0];
            float a0 = bias, a1 = bias, a2 = bias, a3 = bias;
            #pragma unroll
            for (int dy = 0; dy < 5; ++dy) {
                const float* rp = HH2 + (i + dy) * 20 + j0;
                float4 A = *(const float4*)(rp);
                float4 B = *(const float4*)(rp + 4);
                const float* wr = w5 + dy * 5;
                float q0 = wr[0], q1 = wr[1], q2 = wr[2], q3 = wr[3], q4 = wr[4];
                a0 += q0*A.x + q1*A.y + q2*A.z + q3*A.w + q4*B.x;
                a1 += q0*A.y + q1*A.z + q2*A.w + q3*B.x + q4*B.y;
                a2 += q0*A.z + q1*A.w + q2*B.x + q3*B.y + q4*B.z;
                a3 += q0*A.w + q1*B.x + q2*B.y + q3*B.z + q4*B.w;
            }
            *(float4*)(HH2C + i * 20 + j0) = make_float4(a0, a1, a2, a3);
        }
        wave_fence();
        // --- IDWT3 + conv3 fused: 16x8 col-pair items, 2/lane -> LL2P ---
        {
            const float b3c = b3[0];
            #pragma unroll
            for (int k = 0; k < 2; ++k) {
                const int item = lane + 64 * k;
                const int p = item >> 3, c = item & 7;
                const int r = p >> 1;
                const float sr = (p & 1) ? -1.0f : 1.0f;
                float hh = b3c;
                #pragma unroll
                for (int dy = 0; dy < 3; ++dy) {
                    const float* row = HH3 + (r + dy) * 10 + c;
                    const float* wr = w3 + dy * 3;
                    hh += wr[0]*row[0] + wr[1]*row[1] + wr[2]*row[2];
                }
                const int li = (r + 1) * 10 + (c + 1);
                float lo = LL3[li] + sr * LH3[li];
                float hi = HL3[li] + sr * hh;
                *(float2*)(LL2P + p * 20 + 2 * c) =
                    make_float2((lo + hi) * 0.5f, (lo - hi) * 0.5f);
            }
        }
    }
    __syncthreads();   // B2

    // ==== P3: IDWT2 (512 threads, 1 item each): 32x16 col-pair items ====
    {
        const int p = tid >> 4, c = tid & 15;
        const int r = p >> 1;
        const float sr = (p & 1) ? -1.0f : 1.0f;
        const int li = (r + 2) * 20 + (c + 2);
        float lo = LL2P[r * 20 + c] + sr * LH2[li];
        float hi = HL2[li] + sr * HH2C[r * 20 + c];
        *(float2*)(LL1P + p * 36 + 2 * c) =
            make_float2((lo + hi) * 0.5f, (lo - hi) * 0.5f);
    }
    __syncthreads();   // B3

    // ==== P4: IDWT1 -> out (64x64), NT float4 stores, 2 items/thread ====
    #pragma unroll
    for (int k = 0; k < 2; ++k) {
        const int idx = tid + 512 * k;
        const int p = idx >> 4;
        const int c2 = (idx & 15) * 2;
        const int r = p >> 1;
        const float sr = (p & 1) ? -1.0f : 1.0f;
        const int li = (r + 4) * 40 + (c2 + 4);
        const int ci = r * 36 + c2;
        float2 llp = *(const float2*)(LL1P + ci);
        float2 lh  = *(const float2*)(LH1 + li);
        float2 hl  = *(const float2*)(HL1 + li);
        float2 hhc = *(const float2*)(HH1C + ci);
        float lo0 = llp.x + sr * lh.x;
        float hi0 = hl.x + sr * hhc.x;
        float lo1 = llp.y + sr * lh.y;
        float hi1 = hl.y + sr * hhc.y;
        vf4 o = { (lo0 + hi0) * 0.5f, (lo0 - hi0) * 0.5f,
                  (lo1 + hi1) * 0.5f, (lo1 - hi1) * 0.5f };
        __builtin_nontemporal_store(
            o, (vf4*)(out + (size_t)(R0 + p) * IMG_N + C0 + 2 * c2));
    }
}

extern "C" void kernel_launch(void* const* d_in, const int* in_sizes, int n_in,
                              void* d_out, int out_size, void* d_ws, size_t ws_size,
                              hipStream_t stream) {
    (void)in_sizes; (void)n_in; (void)out_size; (void)d_ws; (void)ws_size;
    const float* x  = (const float*)d_in[0];
    const float* w3 = (const float*)d_in[1];
    const float* b3 = (const float*)d_in[2];
    const float* w5 = (const float*)d_in[3];
    const float* b5 = (const float*)d_in[4];
    const float* w7 = (const float*)d_in[5];
    const float* b7 = (const float*)d_in[6];
    float* out = (float*)d_out;

    dim3 grid(IMG_N / 64, IMG_N / 64);     // 64x64 tiles of 64x64 output px
    dim3 block(512);
    haar_fused<<<grid, block, 0, stream>>>(x, w3, b3, w5, b5, w7, b7, out);
}

// Round 6
// 163.951 us; speedup vs baseline: 1.2238x; 1.2238x over previous
//
#include <hip/hip_runtime.h>
#include <stddef.h>

#define IMG_N 4096

typedef float vf4 __attribute__((ext_vector_type(4)));

// LDS layout (float offsets), total 7,824 floats = 31,296 B -> 5 blocks/CU
// (5 x 31.5 KiB rounded < 160 KiB), 256 thr/block -> 20 waves/CU.
// LH1/HL1 stored INTERIOR-ONLY (IDWT1 reads rows/cols 4..35 only): 32x32 @36.
// HH1/LL1 full 40x40 @40. Level-2 20x20 @20, level-3 10x10 @10.
// Aliases (phase-disjoint): HH1C+LL2P -> LL1 slot (LL1 dead after P2 DWT2);
// LL1P -> HH1 slot (HH1 dead after P3 conv7).
#define S_LH1I  0         // 1152
#define S_HL1I  1152      // 1152
#define S_HH1   2304      // 1600
#define S_LL1   3904      // 1600
#define S_LL2   5504      // 400
#define S_LH2   5904      // 400
#define S_HL2   6304      // 400
#define S_HH2   6704      // 400
#define S_LL3   7104      // 100
#define S_LH3   7204      // 100
#define S_HL3   7304      // 100
#define S_HH3   7404      // 100
#define S_HH2C  7504      // 320 (16x16 @20)
#define S_TOTAL 7824

#define S_HH1C  (S_LL1)          // 1152 (32x32 @36), written P3, read P6
#define S_LL2P  (S_LL1 + 1152)   // 320  (16x16 @20), written P4, read P5
#define S_LL1P  (S_HH1)          // 1152 (32x32 @36), written P5, read P6

__global__ __launch_bounds__(256, 5) void haar_fused(
    const float* __restrict__ x,
    const float* __restrict__ w3, const float* __restrict__ b3,
    const float* __restrict__ w5, const float* __restrict__ b5,
    const float* __restrict__ w7, const float* __restrict__ b7,
    float* __restrict__ out)
{
    __shared__ __align__(16) float sm[S_TOTAL];
    const int tid = threadIdx.x;
    const int bx = blockIdx.x, by = blockIdx.y;
    const int R0 = by * 64, C0 = bx * 64;

    float* LH1I = sm + S_LH1I; float* HL1I = sm + S_HL1I;
    float* HH1 = sm + S_HH1;   float* LL1 = sm + S_LL1;
    float* LL2 = sm + S_LL2;   float* LH2 = sm + S_LH2;
    float* HL2 = sm + S_HL2;   float* HH2 = sm + S_HH2;
    float* LL3 = sm + S_LL3;   float* LH3 = sm + S_LH3;
    float* HL3 = sm + S_HL3;   float* HH3 = sm + S_HH3;
    float* HH1C = sm + S_HH1C; float* LL2P = sm + S_LL2P;
    float* HH2C = sm + S_HH2C; float* LL1P = sm + S_LL1P;

    // ==== P1: global load + level-1 DWT. 400 items = 40 rows x 10 groups ====
    // Each item: 2x8 px -> 4 coeff cols of all 4 subbands.
    const bool interior = (by >= 1) && (by <= 62) && (bx >= 1) && (bx <= 62);
    for (int it = tid; it < 400; it += 256) {
        const int u = it / 10, g = it % 10;
        float4 t0, t1, bb0, bb1;
        if (interior) {
            const float* p = x + (size_t)(R0 - 8 + 2 * u) * IMG_N + (C0 - 8 + 8 * g);
            t0  = *(const float4*)(p);
            t1  = *(const float4*)(p + 4);
            bb0 = *(const float4*)(p + IMG_N);
            bb1 = *(const float4*)(p + IMG_N + 4);
        } else {
            const int gr0 = R0 - 8 + 2 * u, gr1 = gr0 + 1;
            const int gc = C0 - 8 + 8 * g;
            const bool r0v = (gr0 >= 0 && gr0 < IMG_N), r1v = (gr1 >= 0 && gr1 < IMG_N);
            float tv[8], bv[8];
            #pragma unroll
            for (int k = 0; k < 8; ++k) {
                int gck = gc + k;
                bool cv = (gck >= 0 && gck < IMG_N);
                tv[k] = (r0v && cv) ? x[(size_t)gr0 * IMG_N + gck] : 0.0f;
                bv[k] = (r1v && cv) ? x[(size_t)gr1 * IMG_N + gck] : 0.0f;
            }
            t0  = make_float4(tv[0], tv[1], tv[2], tv[3]);
            t1  = make_float4(tv[4], tv[5], tv[6], tv[7]);
            bb0 = make_float4(bv[0], bv[1], bv[2], bv[3]);
            bb1 = make_float4(bv[4], bv[5], bv[6], bv[7]);
        }
        float4 llv, lhv, hlv, hhv;
        {
            float a = t0.x, b = t0.y, c = bb0.x, d = bb0.y;
            llv.x = (a + b + c + d) * 0.5f; lhv.x = (a + b - c - d) * 0.5f;
            hlv.x = (a - b + c - d) * 0.5f; hhv.x = (a - b - c + d) * 0.5f;
            a = t0.z; b = t0.w; c = bb0.z; d = bb0.w;
            llv.y = (a + b + c + d) * 0.5f; lhv.y = (a + b - c - d) * 0.5f;
            hlv.y = (a - b + c - d) * 0.5f; hhv.y = (a - b - c + d) * 0.5f;
            a = t1.x; b = t1.y; c = bb1.x; d = bb1.y;
            llv.z = (a + b + c + d) * 0.5f; lhv.z = (a + b - c - d) * 0.5f;
            hlv.z = (a - b + c - d) * 0.5f; hhv.z = (a - b - c + d) * 0.5f;
            a = t1.z; b = t1.w; c = bb1.z; d = bb1.w;
            llv.w = (a + b + c + d) * 0.5f; lhv.w = (a + b - c - d) * 0.5f;
            hlv.w = (a - b + c - d) * 0.5f; hhv.w = (a - b - c + d) * 0.5f;
        }
        const int o = u * 40 + 4 * g;
        *(float4*)(LL1 + o) = llv;
        *(float4*)(HH1 + o) = hhv;
        // LH/HL: only interior rows 4..35, cols 4..35 are ever consumed.
        if (u >= 4 && u < 36 && g >= 1 && g <= 8) {
            const int oi = (u - 4) * 36 + (4 * g - 4);
            *(float4*)(LH1I + oi) = lhv;
            *(float4*)(HL1I + oi) = hlv;
        }
    }
    __syncthreads();   // B1

    // ==== P2: DWT2 (threads 0-99): LL1 40x40@40 -> level-2 20x20@20 ====
    if (tid < 100) {
        const int u = tid / 5, g = tid % 5;
        const float* rp = LL1 + (2 * u) * 40 + 8 * g;
        float4 t0 = *(const float4*)(rp),      t1 = *(const float4*)(rp + 4);
        float4 c0 = *(const float4*)(rp + 40), c1 = *(const float4*)(rp + 44);
        float4 llv, lhv, hlv, hhv;
        llv.x = (t0.x + t0.y + c0.x + c0.y) * 0.5f; lhv.x = (t0.x + t0.y - c0.x - c0.y) * 0.5f;
        hlv.x = (t0.x - t0.y + c0.x - c0.y) * 0.5f; hhv.x = (t0.x - t0.y - c0.x + c0.y) * 0.5f;
        llv.y = (t0.z + t0.w + c0.z + c0.w) * 0.5f; lhv.y = (t0.z + t0.w - c0.z - c0.w) * 0.5f;
        hlv.y = (t0.z - t0.w + c0.z - c0.w) * 0.5f; hhv.y = (t0.z - t0.w - c0.z + c0.w) * 0.5f;
        llv.z = (t1.x + t1.y + c1.x + c1.y) * 0.5f; lhv.z = (t1.x + t1.y - c1.x - c1.y) * 0.5f;
        hlv.z = (t1.x - t1.y + c1.x - c1.y) * 0.5f; hhv.z = (t1.x - t1.y - c1.x + c1.y) * 0.5f;
        llv.w = (t1.z + t1.w + c1.z + c1.w) * 0.5f; lhv.w = (t1.z + t1.w - c1.z - c1.w) * 0.5f;
        hlv.w = (t1.z - t1.w + c1.z - c1.w) * 0.5f; hhv.w = (t1.z - t1.w - c1.z + c1.w) * 0.5f;
        const int o = u * 20 + 4 * g;
        *(float4*)(LL2 + o) = llv;  *(float4*)(LH2 + o) = lhv;
        *(float4*)(HL2 + o) = hlv;  *(float4*)(HH2 + o) = hhv;
    }
    __syncthreads();   // B2

    // ==== P3: conv7 on waves 0-1 || DWT3 on wave 2 || conv5 on wave 3 ====
    if (tid < 128) {
        // conv7 on HH1: 2x4-output strip per thread (out rows 2*i2, 2*i2+1).
        // Out row rr taps HH1 rows rr+1..rr+7, out col j taps cols j+1..j+7.
        const int i2 = tid >> 3;            // 0..15
        const int j0 = (tid & 7) << 2;      // 0,4,...,28
        const float bias = b7[0];
        float a0 = bias, a1 = bias, a2 = bias, a3 = bias;   // row 2*i2
        float c0 = bias, c1 = bias, c2 = bias, c3 = bias;   // row 2*i2+1
        #pragma unroll
        for (int k = 0; k < 8; ++k) {       // HH1 rows 2*i2+1+k (max 39)
            const float* rp = HH1 + (2 * i2 + 1 + k) * 40 + j0;
            float4 A = *(const float4*)(rp);
            float4 B = *(const float4*)(rp + 4);
            float4 C = *(const float4*)(rp + 8);
            if (k <= 6) {                   // dy = k for out row 2*i2
                const float* wr = w7 + k * 7;
                float q0 = wr[0], q1 = wr[1], q2 = wr[2], q3 = wr[3],
                      q4 = wr[4], q5 = wr[5], q6 = wr[6];
                a0 += q0*A.y + q1*A.z + q2*A.w + q3*B.x + q4*B.y + q5*B.z + q6*B.w;
                a1 += q0*A.z + q1*A.w + q2*B.x + q3*B.y + q4*B.z + q5*B.w + q6*C.x;
                a2 += q0*A.w + q1*B.x + q2*B.y + q3*B.z + q4*B.w + q5*C.x + q6*C.y;
                a3 += q0*B.x + q1*B.y + q2*B.z + q3*B.w + q4*C.x + q5*C.y + q6*C.z;
            }
            if (k >= 1) {                   // dy = k-1 for out row 2*i2+1
                const float* wr = w7 + (k - 1) * 7;
                float q0 = wr[0], q1 = wr[1], q2 = wr[2], q3 = wr[3],
                      q4 = wr[4], q5 = wr[5], q6 = wr[6];
                c0 += q0*A.y + q1*A.z + q2*A.w + q3*B.x + q4*B.y + q5*B.z + q6*B.w;
                c1 += q0*A.z + q1*A.w + q2*B.x + q3*B.y + q4*B.z + q5*B.w + q6*C.x;
                c2 += q0*A.w + q1*B.x + q2*B.y + q3*B.z + q4*B.w + q5*C.x + q6*C.y;
                c3 += q0*B.x + q1*B.y + q2*B.z + q3*B.w + q4*C.x + q5*C.y + q6*C.z;
            }
        }
        *(float4*)(HH1C + (2 * i2) * 36 + j0)     = make_float4(a0, a1, a2, a3);
        *(float4*)(HH1C + (2 * i2 + 1) * 36 + j0) = make_float4(c0, c1, c2, c3);
    } else if (tid < 192) {
        // DWT3: LL2 20x20@20 -> level-3 10x10@10 (50 items on wave 2)
        const int t = tid - 128;
        if (t < 50) {
            const int u = t / 5, v2 = (t % 5) * 2;
            const float* rp = LL2 + (2 * u) * 20 + 2 * v2;
            float4 t0 = *(const float4*)(rp);
            float4 c0 = *(const float4*)(rp + 20);
            const int o = u * 10 + v2;
            *(float2*)(LL3 + o) = make_float2((t0.x + t0.y + c0.x + c0.y) * 0.5f,
                                              (t0.z + t0.w + c0.z + c0.w) * 0.5f);
            *(float2*)(LH3 + o) = make_float2((t0.x + t0.y - c0.x - c0.y) * 0.5f,
                                              (t0.z + t0.w - c0.z - c0.w) * 0.5f);
            *(float2*)(HL3 + o) = make_float2((t0.x - t0.y + c0.x - c0.y) * 0.5f,
                                              (t0.z - t0.w + c0.z - c0.w) * 0.5f);
            *(float2*)(HH3 + o) = make_float2((t0.x - t0.y - c0.x + c0.y) * 0.5f,
                                              (t0.z - t0.w - c0.z + c0.w) * 0.5f);
        }
    } else {
        // conv5 on HH2: 16x16 outputs, 1x4 strip per thread (64 strips, wave 3)
        const int s = tid - 192;
        const int i = s >> 2;
        const int j0 = (s & 3) << 2;
        const float bias = b5[0];
        float a0 = bias, a1 = bias, a2 = bias, a3 = bias;
        #pragma unroll
        for (int dy = 0; dy < 5; ++dy) {
            const float* rp = HH2 + (i + dy) * 20 + j0;
            float4 A = *(const float4*)(rp);
            float4 B = *(const float4*)(rp + 4);
            const float* wr = w5 + dy * 5;
            float q0 = wr[0], q1 = wr[1], q2 = wr[2], q3 = wr[3], q4 = wr[4];
            a0 += q0*A.x + q1*A.y + q2*A.z + q3*A.w + q4*B.x;
            a1 += q0*A.y + q1*A.z + q2*A.w + q3*B.x + q4*B.y;
            a2 += q0*A.z + q1*A.w + q2*B.x + q3*B.y + q4*B.z;
            a3 += q0*A.w + q1*B.x + q2*B.y + q3*B.z + q4*B.w;
        }
        *(float4*)(HH2C + i * 20 + j0) = make_float4(a0, a1, a2, a3);
    }
    __syncthreads();   // B3

    // ==== P4: IDWT3 + conv3 fused (threads 0-127): 16x8 col-pair items ====
    if (tid < 128) {
        const int p = tid >> 3, c = tid & 7;
        const int r = p >> 1;
        const float sr = (p & 1) ? -1.0f : 1.0f;
        float hh = b3[0];
        #pragma unroll
        for (int dy = 0; dy < 3; ++dy) {
            const float* row = HH3 + (r + dy) * 10 + c;
            const float* wr = w3 + dy * 3;
            hh += wr[0]*row[0] + wr[1]*row[1] + wr[2]*row[2];
        }
        const int li = (r + 1) * 10 + (c + 1);
        float lo = LL3[li] + sr * LH3[li];
        float hi = HL3[li] + sr * hh;
        *(float2*)(LL2P + p * 20 + 2 * c) =
            make_float2((lo + hi) * 0.5f, (lo - hi) * 0.5f);
    }
    __syncthreads();   // B4

    // ==== P5: IDWT2 (512 items, 2/thread): 32x16 col-pair items ====
    #pragma unroll
    for (int k = 0; k < 2; ++k) {
        const int idx = tid + 256 * k;
        const int p = idx >> 4, c = idx & 15;
        const int r = p >> 1;
        const float sr = (p & 1) ? -1.0f : 1.0f;
        const int li = (r + 2) * 20 + (c + 2);
        float lo = LL2P[r * 20 + c] + sr * LH2[li];
        float hi = HL2[li] + sr * HH2C[r * 20 + c];
        *(float2*)(LL1P + p * 36 + 2 * c) =
            make_float2((lo + hi) * 0.5f, (lo - hi) * 0.5f);
    }
    __syncthreads();   // B5

    // ==== P6: IDWT1 -> out (64x64), NT float4 stores, 4 items/thread ====
    #pragma unroll
    for (int k = 0; k < 4; ++k) {
        const int idx = tid + 256 * k;
        const int p = idx >> 4;             // out row 0..63
        const int c2 = (idx & 15) * 2;      // coeff col base (interior coords)
        const int r = p >> 1;
        const float sr = (p & 1) ? -1.0f : 1.0f;
        const int ci = r * 36 + c2;         // shared index: LH1I/HL1I/HH1C/LL1P
        float2 llp = *(const float2*)(LL1P + ci);
        float2 lh  = *(const float2*)(LH1I + ci);
        float2 hl  = *(const float2*)(HL1I + ci);
        float2 hhc = *(const float2*)(HH1C + ci);
        float lo0 = llp.x + sr * lh.x;
        float hi0 = hl.x + sr * hhc.x;
        float lo1 = llp.y + sr * lh.y;
        float hi1 = hl.y + sr * hhc.y;
        vf4 o = { (lo0 + hi0) * 0.5f, (lo0 - hi0) * 0.5f,
                  (lo1 + hi1) * 0.5f, (lo1 - hi1) * 0.5f };
        __builtin_nontemporal_store(
            o, (vf4*)(out + (size_t)(R0 + p) * IMG_N + C0 + 2 * c2));
    }
}

extern "C" void kernel_launch(void* const* d_in, const int* in_sizes, int n_in,
                              void* d_out, int out_size, void* d_ws, size_t ws_size,
                              hipStream_t stream) {
    (void)in_sizes; (void)n_in; (void)out_size; (void)d_ws; (void)ws_size;
    const float* x  = (const float*)d_in[0];
    const float* w3 = (const float*)d_in[1];
    const float* b3 = (const float*)d_in[2];
    const float* w5 = (const float*)d_in[3];
    const float* b5 = (const float*)d_in[4];
    const float* w7 = (const float*)d_in[5];
    const float* b7 = (const float*)d_in[6];
    float* out = (float*)d_out;

    dim3 grid(IMG_N / 64, IMG_N / 64);     // 64x64 tiles of 64x64 output px
    dim3 block(256);
    haar_fused<<<grid, block, 0, stream>>>(x, w3, b3, w5, b5, w7, b7, out);
}